// Round 17
// baseline (3777.556 us; speedup 1.0000x reference)
//
#include <hip/hip_runtime.h>
#include <math.h>

#define BB 8
#define NN 4096
#define KNN 20
#define EPSBN 1e-5f

__device__ __forceinline__ float lrelu(float x){ return x > 0.f ? x : 0.2f*x; }
__device__ __forceinline__ unsigned encf(float f){
  unsigned u = __float_as_uint(f);
  return (u & 0x80000000u) ? ~u : (u | 0x80000000u);
}
__device__ __forceinline__ float decf(unsigned u){
  return (u & 0x80000000u) ? __uint_as_float(u & 0x7fffffffu) : __uint_as_float(~u);
}
__device__ __forceinline__ float rdlane(float v, int l){
  return __uint_as_float(__builtin_amdgcn_readlane(__float_as_uint(v), l));
}

// ---- weight prep: dst[i][O..] = src[o][coff+i] * g[o]/sqrt(1+eps) ----
__global__ void prep_w(float* __restrict__ dst, const float* __restrict__ src,
                       int O, int I, int ld, int coff, const float* __restrict__ g){
  int tot = O*I;
  for(int t = blockIdx.x*blockDim.x + threadIdx.x; t < tot; t += gridDim.x*blockDim.x){
    int o = t % O, i = t / O;
    float s = g ? g[o] * (1.0f/sqrtf(1.0f+EPSBN)) : 1.0f;
    dst[(size_t)i*O + o] = src[(size_t)o*ld + coff + i] * s;
  }
}

__global__ void init_gmax(unsigned* __restrict__ g){
  int t = blockIdx.x*blockDim.x + threadIdx.x;
  if(t < BB*1024) g[t] = 0u;
}

__global__ void build_x0(const float* __restrict__ coords, const float* __restrict__ feats,
                         float* __restrict__ x0p){
  int p = blockIdx.x*blockDim.x + threadIdx.x;
  if(p >= BB*NN) return;
  int b = p / NN, n = p % NN;
  x0p[(size_t)p*6+0] = coords[(size_t)p*3+0];
  x0p[(size_t)p*6+1] = coords[(size_t)p*3+1];
  x0p[(size_t)p*6+2] = coords[(size_t)p*3+2];
  #pragma unroll
  for(int cc=0; cc<3; ++cc) x0p[(size_t)p*6+3+cc] = feats[((size_t)b*3+cc)*NN + n];
}

// ---- kNN: 256 threads (4 waves), 8 queries/block, 2 row-streams per thread
//      so each xi LDS read serves TWO rows (fill was LDS-pipe-bound at 512thr).
//      Each wave feeds 2 selection stacks (queries 2w, 2w+1); selection =
//      proven 3-deep register stack + exact butterfly + owner pop + rare
//      bitwise-identical refill. stage[buf][q][i] = dist(row s*512+i, q). ----
template<int D, int LD>
__global__ __launch_bounds__(256,4) void knn_kernel(const float* __restrict__ X, int coloff,
                                                    int* __restrict__ idxOut){
  constexpr int IG = 8;
  __shared__ float stage[2][IG][512];
  __shared__ float xi_s[IG][(D+3)&~3];
  __shared__ float sqi_s[IG];
  const int t = threadIdx.x;           // 0..255
  const int w = t >> 6, l = t & 63;    // wave 0..3
  const int b = blockIdx.x / (NN/IG);
  const int i0 = (blockIdx.x % (NN/IG)) * IG;
  const float* Xb = X + (size_t)b*NN*LD + coloff;

  for(int u = t; u < IG*D; u += 256) xi_s[u/D][u%D] = Xb[(size_t)(i0 + u/D)*LD + (u%D)];
  __syncthreads();
  if(t < IG){
    float s = 0.f;
    for(int d=0; d<D; ++d){ float v = xi_s[t][d]; s = fmaf(v, v, s); }
    sqi_s[t] = s;
  }
  __syncthreads();

  // two per-lane exact top-3 stacks: A = query 2w, B = query 2w+1
  float vA1=-INFINITY,vA2=-INFINITY,vA3=-INFINITY;
  int   jA1=0x7fffffff,jA2=0x7fffffff,jA3=0x7fffffff;
  float vB1=-INFINITY,vB2=-INFINITY,vB3=-INFINITY;
  int   jB1=0x7fffffff,jB2=0x7fffffff,jB3=0x7fffffff;
  auto insA = [&](float v, int jj){
    bool b1 = v > vA1, b2 = v > vA2, b3 = v > vA3;
    vA3 = b3 ? (b2 ? vA2 : v) : vA3;  jA3 = b3 ? (b2 ? jA2 : jj) : jA3;
    vA2 = b2 ? (b1 ? vA1 : v) : vA2;  jA2 = b2 ? (b1 ? jA1 : jj) : jA2;
    vA1 = b1 ? v : vA1;               jA1 = b1 ? jj : jA1;
  };
  auto insB = [&](float v, int jj){
    bool b1 = v > vB1, b2 = v > vB2, b3 = v > vB3;
    vB3 = b3 ? (b2 ? vB2 : v) : vB3;  jB3 = b3 ? (b2 ? jB2 : jj) : jB3;
    vB2 = b2 ? (b1 ? vB1 : v) : vB2;  jB2 = b2 ? (b1 ? jB1 : jj) : jB2;
    vB1 = b1 ? v : vB1;               jB1 = b1 ? jj : jB1;
  };

  const int qa = 2*w, qb = 2*w + 1;

  for(int s = 0; s < NN/512; ++s){
    const int jA = s*512 + t;
    const int jB = jA + 256;
    const float* rowA = Xb + (size_t)jA*LD;
    const float* rowB = Xb + (size_t)jB*LD;
    float dA[IG], dB[IG];
    #pragma unroll
    for(int q=0;q<IG;++q){ dA[q] = 0.f; dB[q] = 0.f; }
    float sqA = 0.f, sqB = 0.f;
    if constexpr (D % 4 == 0){
      #pragma unroll
      for(int c=0; c<D/4; ++c){
        const float4 va = *reinterpret_cast<const float4*>(rowA + c*4);
        const float4 vb = *reinterpret_cast<const float4*>(rowB + c*4);
        sqA = fmaf(va.x,va.x,sqA); sqA = fmaf(va.y,va.y,sqA);
        sqA = fmaf(va.z,va.z,sqA); sqA = fmaf(va.w,va.w,sqA);
        sqB = fmaf(vb.x,vb.x,sqB); sqB = fmaf(vb.y,vb.y,sqB);
        sqB = fmaf(vb.z,vb.z,sqB); sqB = fmaf(vb.w,vb.w,sqB);
        #pragma unroll
        for(int q=0;q<IG;++q){
          const float4 xw = *reinterpret_cast<const float4*>(&xi_s[q][c*4]);
          float a = dA[q];
          a = fmaf(va.x,xw.x,a); a = fmaf(va.y,xw.y,a);
          a = fmaf(va.z,xw.z,a); a = fmaf(va.w,xw.w,a);
          dA[q] = a;
          float bq = dB[q];
          bq = fmaf(vb.x,xw.x,bq); bq = fmaf(vb.y,xw.y,bq);
          bq = fmaf(vb.z,xw.z,bq); bq = fmaf(vb.w,xw.w,bq);
          dB[q] = bq;
        }
      }
    } else {
      #pragma unroll
      for(int d0=0; d0<D; ++d0){
        float va = rowA[d0], vb = rowB[d0];
        sqA = fmaf(va,va,sqA);
        sqB = fmaf(vb,vb,sqB);
        #pragma unroll
        for(int q=0;q<IG;++q){
          float xw = xi_s[q][d0];
          dA[q] = fmaf(va, xw, dA[q]);
          dB[q] = fmaf(vb, xw, dB[q]);
        }
      }
    }
    const int buf = s & 1;
    #pragma unroll
    for(int q=0;q<IG;++q){
      stage[buf][q][t]       = 2.f*dA[q] - sqA - sqi_s[q];
      stage[buf][q][256 + t] = 2.f*dB[q] - sqB - sqi_s[q];
    }
    __syncthreads();
    {
      const float4 va0 = *reinterpret_cast<const float4*>(&stage[buf][qa][4*l]);
      const int ja0 = s*512 + 4*l;
      insA(va0.x, ja0+0); insA(va0.y, ja0+1); insA(va0.z, ja0+2); insA(va0.w, ja0+3);
      const float4 va1 = *reinterpret_cast<const float4*>(&stage[buf][qa][256 + 4*l]);
      const int ja1 = s*512 + 256 + 4*l;
      insA(va1.x, ja1+0); insA(va1.y, ja1+1); insA(va1.z, ja1+2); insA(va1.w, ja1+3);
      const float4 vb0 = *reinterpret_cast<const float4*>(&stage[buf][qb][4*l]);
      insB(vb0.x, ja0+0); insB(vb0.y, ja0+1); insB(vb0.z, ja0+2); insB(vb0.w, ja0+3);
      const float4 vb1 = *reinterpret_cast<const float4*>(&stage[buf][qb][256 + 4*l]);
      insB(vb1.x, ja1+0); insB(vb1.y, ja1+1); insB(vb1.z, ja1+2); insB(vb1.w, ja1+3);
    }
  }

  // ---- selection for query A (2w) ----
  {
    int* outRow = idxOut + (size_t)(b*NN + i0 + qa)*KNN;
    const float sqi = sqi_s[qa];
    #pragma unroll 1
    for(int r=0;r<KNN;++r){
      float bv = vA1; int bj = jA1;
      #pragma unroll
      for(int off = 1; off < 64; off <<= 1){
        float ov = __shfl_xor(bv, off, 64);
        int oj = __shfl_xor(bj, off, 64);
        bool better = (ov > bv) || (ov == bv && oj < bj);
        bv = better ? ov : bv;
        bj = better ? oj : bj;
      }
      if(l == 0) outRow[r] = bj;
      if(((bj & 255) >> 2) == l){
        const float ve = vA1; const int je = jA1;
        vA1=vA2; jA1=jA2; vA2=vA3; jA2=jA3; vA3=-INFINITY; jA3=0x7fffffff;
        if(jA1 == 0x7fffffff){
          #pragma unroll 1
          for(int s2=0; s2<NN/512; ++s2){
            #pragma unroll 1
            for(int h=0; h<2; ++h){
              #pragma unroll
              for(int e=0; e<4; ++e){
                const int jj = s2*512 + h*256 + 4*l + e;
                const float* rowp = Xb + (size_t)jj*LD;
                float dotv=0.f, sq=0.f;
                if constexpr (D % 4 == 0){
                  #pragma unroll 4
                  for(int c=0; c<D/4; ++c){
                    const float4 v = *reinterpret_cast<const float4*>(rowp + c*4);
                    sq = fmaf(v.x,v.x,sq); sq = fmaf(v.y,v.y,sq);
                    sq = fmaf(v.z,v.z,sq); sq = fmaf(v.w,v.w,sq);
                    const float4 xw = *reinterpret_cast<const float4*>(&xi_s[qa][c*4]);
                    dotv = fmaf(v.x,xw.x,dotv); dotv = fmaf(v.y,xw.y,dotv);
                    dotv = fmaf(v.z,xw.z,dotv); dotv = fmaf(v.w,xw.w,dotv);
                  }
                } else {
                  #pragma unroll
                  for(int d0=0; d0<D; ++d0){
                    float v = rowp[d0];
                    sq = fmaf(v,v,sq);
                    dotv = fmaf(v, xi_s[qa][d0], dotv);
                  }
                }
                const float dq = 2.f*dotv - sq - sqi;
                const bool ok = (dq < ve) || (dq == ve && jj > je);
                if(ok) insA(dq, jj);
              }
            }
          }
        }
      }
    }
  }

  // ---- selection for query B (2w+1) ----
  {
    int* outRow = idxOut + (size_t)(b*NN + i0 + qb)*KNN;
    const float sqi = sqi_s[qb];
    #pragma unroll 1
    for(int r=0;r<KNN;++r){
      float bv = vB1; int bj = jB1;
      #pragma unroll
      for(int off = 1; off < 64; off <<= 1){
        float ov = __shfl_xor(bv, off, 64);
        int oj = __shfl_xor(bj, off, 64);
        bool better = (ov > bv) || (ov == bv && oj < bj);
        bv = better ? ov : bv;
        bj = better ? oj : bj;
      }
      if(l == 0) outRow[r] = bj;
      if(((bj & 255) >> 2) == l){
        const float ve = vB1; const int je = jB1;
        vB1=vB2; jB1=jB2; vB2=vB3; jB2=jB3; vB3=-INFINITY; jB3=0x7fffffff;
        if(jB1 == 0x7fffffff){
          #pragma unroll 1
          for(int s2=0; s2<NN/512; ++s2){
            #pragma unroll 1
            for(int h=0; h<2; ++h){
              #pragma unroll
              for(int e=0; e<4; ++e){
                const int jj = s2*512 + h*256 + 4*l + e;
                const float* rowp = Xb + (size_t)jj*LD;
                float dotv=0.f, sq=0.f;
                if constexpr (D % 4 == 0){
                  #pragma unroll 4
                  for(int c=0; c<D/4; ++c){
                    const float4 v = *reinterpret_cast<const float4*>(rowp + c*4);
                    sq = fmaf(v.x,v.x,sq); sq = fmaf(v.y,v.y,sq);
                    sq = fmaf(v.z,v.z,sq); sq = fmaf(v.w,v.w,sq);
                    const float4 xw = *reinterpret_cast<const float4*>(&xi_s[qb][c*4]);
                    dotv = fmaf(v.x,xw.x,dotv); dotv = fmaf(v.y,xw.y,dotv);
                    dotv = fmaf(v.z,xw.z,dotv); dotv = fmaf(v.w,xw.w,dotv);
                  }
                } else {
                  #pragma unroll
                  for(int d0=0; d0<D; ++d0){
                    float v = rowp[d0];
                    sq = fmaf(v,v,sq);
                    dotv = fmaf(v, xi_s[qb][d0], dotv);
                  }
                }
                const float dq = 2.f*dotv - sq - sqi;
                const bool ok = (dq < ve) || (dq == ve && jj > je);
                if(ok) insB(dq, jj);
              }
            }
          }
        }
      }
    }
  }
}

// ---- EdgeConv: weights in registers, readlane broadcasts, no LDS, no barriers ----
template<int DIN, int NL>
__global__ __launch_bounds__(64,3) void edgeconv_k(
    const float* __restrict__ xin, int ldin, int cin_off,
    const int* __restrict__ idx,
    const float* __restrict__ WaT, const float* __restrict__ ba,
    const float* __restrict__ WbT, const float* __restrict__ bb,
    float* __restrict__ xout, int ldout, int cout_off){
  constexpr int PPB = 4;
  const int c = threadIdx.x;           // output channel 0..63
  float wa[DIN];
  #pragma unroll
  for(int d=0; d<DIN; ++d) wa[d] = WaT[d*64 + c];
  float wb[(NL==2)?64:1];
  if constexpr (NL==2){
    #pragma unroll
    for(int d=0; d<64; ++d) wb[d] = WbT[d*64 + c];
  }
  const float bac = ba[c];
  const float bbc = (NL==2) ? bb[c] : 0.f;

  for(int pp=0; pp<PPB; ++pp){
    const int p = blockIdx.x*PPB + pp;
    const int b = p / NN;
    float ctr = (c < DIN) ? xin[(size_t)p*ldin + cin_off + c] : 0.f;
    float bacc[4] = {};
    #pragma unroll
    for(int d=0; d<DIN; ++d)
      bacc[d&3] += rdlane(ctr, d) * (WaT[(DIN+d)*64 + c] - wa[d]);
    const float base = bacc[0]+bacc[1]+bacc[2]+bacc[3];

    const int* irow = idx + (size_t)p*KNN;
    int myidx = (c < KNN) ? irow[c] : 0;
    float vmax = -INFINITY;
    int j0 = __builtin_amdgcn_readlane(myidx, 0);
    float nbr = (c < DIN) ? xin[(size_t)(b*NN + j0)*ldin + cin_off + c] : 0.f;
    for(int k=0; k<KNN; ++k){
      float nbrn = 0.f;
      if(k+1 < KNN){
        int jn = __builtin_amdgcn_readlane(myidx, k+1);
        nbrn = (c < DIN) ? xin[(size_t)(b*NN + jn)*ldin + cin_off + c] : 0.f;
      }
      float hacc[4] = {};
      #pragma unroll
      for(int d=0; d<DIN; ++d) hacc[d&3] += rdlane(nbr, d) * wa[d];
      float a1 = lrelu(base + hacc[0]+hacc[1]+hacc[2]+hacc[3] + bac);
      if constexpr (NL==2){
        float g[4] = {};
        #pragma unroll
        for(int d=0; d<64; ++d) g[d&3] += rdlane(a1, d) * wb[d];
        vmax = fmaxf(vmax, lrelu(g[0]+g[1]+g[2]+g[3] + bbc));
      } else {
        vmax = fmaxf(vmax, a1);
      }
      nbr = nbrn;
    }
    xout[(size_t)p*ldout + cout_off + c] = vmax;
  }
}

// ---- generic fp32 GEMM: C[M][Nw] = A[M][K] @ Bm[K][Nw], 64x64 tile, 4x4 microtile ----
template<int EPI>
__global__ __launch_bounds__(256) void gemm_k(
    const float* __restrict__ A, int lda,
    const float* __restrict__ Bm, int Nw, int Ksz,
    const float* __restrict__ bias_n, const float* __restrict__ bias_bn,
    float* __restrict__ C, int ldc, unsigned* __restrict__ gmaxE){
  constexpr int ST = 68;
  __shared__ float At[32*ST];
  __shared__ float Bt[32*ST];
  const int t = threadIdx.x;
  const int m0 = blockIdx.x * 64;
  const int n0 = blockIdx.y * 64;
  const int tm = t >> 4, tn = t & 15;
  float acc[4][4] = {};
  for(int k0 = 0; k0 < Ksz; k0 += 32){
    #pragma unroll
    for(int r=0;r<2;++r){
      int lin = r*256 + t;
      int m = lin >> 3, f4 = lin & 7;
      float4 v = *reinterpret_cast<const float4*>(A + (size_t)(m0+m)*lda + k0 + f4*4);
      At[(f4*4+0)*ST + m] = v.x; At[(f4*4+1)*ST + m] = v.y;
      At[(f4*4+2)*ST + m] = v.z; At[(f4*4+3)*ST + m] = v.w;
    }
    #pragma unroll
    for(int r=0;r<2;++r){
      int lin = r*256 + t;
      int kk = lin >> 4, n4 = lin & 15;
      float4 v = *reinterpret_cast<const float4*>(Bm + (size_t)(k0+kk)*Nw + n0 + n4*4);
      *reinterpret_cast<float4*>(&Bt[kk*ST + n4*4]) = v;
    }
    __syncthreads();
    #pragma unroll
    for(int kk=0; kk<32; ++kk){
      float4 a4 = *reinterpret_cast<const float4*>(&At[kk*ST + tm*4]);
      float4 b4 = *reinterpret_cast<const float4*>(&Bt[kk*ST + tn*4]);
      float av[4] = {a4.x,a4.y,a4.z,a4.w};
      float bw[4] = {b4.x,b4.y,b4.z,b4.w};
      #pragma unroll
      for(int i2=0;i2<4;++i2)
        #pragma unroll
        for(int q=0;q<4;++q) acc[i2][q] += av[i2]*bw[q];
    }
    __syncthreads();
  }
  const int b = m0 / NN;
  if constexpr (EPI == 0){
    float* colm = At;  // reuse (post-barrier)
    #pragma unroll
    for(int q=0;q<4;++q){
      int n = n0 + tn*4 + q;
      float bn = bias_n[n];
      float mx = -INFINITY;
      #pragma unroll
      for(int r2=0;r2<4;++r2) mx = fmaxf(mx, lrelu(acc[r2][q] + bn));
      colm[tm*64 + tn*4 + q] = mx;
    }
    __syncthreads();
    if(t < 64){
      float mx = -INFINITY;
      #pragma unroll
      for(int r2=0;r2<16;++r2) mx = fmaxf(mx, colm[r2*64 + t]);
      atomicMax(gmaxE + b*1024 + n0 + t, encf(mx));
    }
  } else {
    #pragma unroll
    for(int r2=0;r2<4;++r2){
      int row = m0 + tm*4 + r2;
      float4 vo;
      float vv[4];
      #pragma unroll
      for(int q=0;q<4;++q){
        int n = n0 + tn*4 + q;
        float v = acc[r2][q];
        if constexpr (EPI == 1) v += bias_bn[b*512 + n] + bias_n[n];
        else v += bias_n[n];
        vv[q] = lrelu(v);
      }
      vo.x=vv[0]; vo.y=vv[1]; vo.z=vv[2]; vo.w=vv[3];
      *reinterpret_cast<float4*>(C + (size_t)row*ldc + n0 + tn*4) = vo;
    }
  }
}

// ---- bias7[b][o] = s7[o] * sum_c w7[o][c] * gmax[b][c] ----
__global__ __launch_bounds__(256) void bias7_kernel(const unsigned* __restrict__ gmaxE,
    const float* __restrict__ w7, const float* __restrict__ g7, float* __restrict__ b7p){
  __shared__ float gm[1024];
  const int t = threadIdx.x;
  const int b = blockIdx.x, half = blockIdx.y;
  for(int u=t; u<1024; u+=256) gm[u] = decf(gmaxE[b*1024+u]);
  __syncthreads();
  const int o = half*256 + t;
  const float* row = w7 + (size_t)o*1216;
  float acc = 0.f;
  for(int d0=0; d0<1024; d0+=4){
    float4 v = *reinterpret_cast<const float4*>(row + d0);
    acc += v.x*gm[d0] + v.y*gm[d0+1] + v.z*gm[d0+2] + v.w*gm[d0+3];
  }
  b7p[b*512+o] = acc * (g7[o] * (1.0f/sqrtf(1.0f+EPSBN)));
}

// ---- conv9: [32768][256] @ w9^T[256][20] -> out[32768][20] ----
__global__ __launch_bounds__(64) void conv9_kernel(const float* __restrict__ y8,
    const float* __restrict__ w9, float* __restrict__ out){
  const int p = blockIdx.x*64 + threadIdx.x;
  float acc[20] = {};
  const float* row = y8 + (size_t)p*256;
  for(int d0=0; d0<256; d0+=4){
    float4 v = *reinterpret_cast<const float4*>(row + d0);
    #pragma unroll
    for(int o=0;o<20;++o){
      float4 w = *reinterpret_cast<const float4*>(w9 + o*256 + d0);
      acc[o] += v.x*w.x + v.y*w.y + v.z*w.z + v.w*w.w;
    }
  }
  #pragma unroll
  for(int o=0;o<20;++o) out[(size_t)p*20+o] = acc[o];
}

extern "C" void kernel_launch(void* const* d_in, const int* in_sizes, int n_in,
                              void* d_out, int out_size, void* d_ws, size_t ws_size,
                              hipStream_t stream){
  const float* coords = (const float*)d_in[0];
  const float* feats  = (const float*)d_in[1];
  const float* w1 = (const float*)d_in[2];
  const float* w2 = (const float*)d_in[3];
  const float* w3 = (const float*)d_in[4];
  const float* w4 = (const float*)d_in[5];
  const float* w5 = (const float*)d_in[6];
  const float* w6 = (const float*)d_in[7];
  const float* w7 = (const float*)d_in[8];
  const float* w8 = (const float*)d_in[9];
  const float* w9 = (const float*)d_in[10];
  const float* g15 = (const float*)d_in[11];
  const float* b15 = (const float*)d_in[12];
  const float* g6 = (const float*)d_in[13];
  const float* b6 = (const float*)d_in[14];
  const float* g7 = (const float*)d_in[15];
  const float* b7 = (const float*)d_in[16];
  const float* g8 = (const float*)d_in[17];
  const float* b8 = (const float*)d_in[18];
  float* out = (float*)d_out;
  float* ws = (float*)d_ws;

  size_t off = 0;
  float* xc   = ws + off; off += (size_t)BB*NN*192;
  float* x0p  = ws + off; off += (size_t)BB*NN*6;
  int*   idx  = (int*)(ws + off); off += (size_t)BB*NN*KNN;
  unsigned* gmaxE = (unsigned*)(ws + off); off += BB*1024;
  float* b7p  = ws + off; off += BB*512;
  float* w1t  = ws + off; off += 12*64;
  float* w2t  = ws + off; off += 64*64;
  float* w3t  = ws + off; off += 128*64;
  float* w4t  = ws + off; off += 64*64;
  float* w5t  = ws + off; off += 128*64;
  float* w6t  = ws + off; off += (size_t)192*1024;
  float* w7lt = ws + off; off += (size_t)192*512;
  float* w8t  = ws + off; off += (size_t)512*256;
  float* y7   = ws + off; off += (size_t)BB*NN*512;
  float* y8   = ws + off; off += (size_t)BB*NN*256;

  auto gb = [](int n){ return dim3((unsigned)((n + 255)/256)); };

  prep_w<<<gb(64*12),  256,0,stream>>>(w1t, w1, 64, 12, 12, 0, g15 + 0);
  prep_w<<<gb(64*64),  256,0,stream>>>(w2t, w2, 64, 64, 64, 0, g15 + 64);
  prep_w<<<gb(64*128), 256,0,stream>>>(w3t, w3, 64, 128, 128, 0, g15 + 128);
  prep_w<<<gb(64*64),  256,0,stream>>>(w4t, w4, 64, 64, 64, 0, g15 + 192);
  prep_w<<<gb(64*128), 256,0,stream>>>(w5t, w5, 64, 128, 128, 0, g15 + 256);
  prep_w<<<gb(1024*192),256,0,stream>>>(w6t, w6, 1024, 192, 192, 0, g6);
  prep_w<<<gb(512*192),256,0,stream>>>(w7lt, w7, 512, 192, 1216, 1024, g7);
  prep_w<<<gb(256*512),256,0,stream>>>(w8t, w8, 256, 512, 512, 0, g8);
  init_gmax<<<gb(BB*1024),256,0,stream>>>(gmaxE);
  build_x0<<<gb(BB*NN),256,0,stream>>>(coords, feats, x0p);

  knn_kernel<3,3><<<BB*(NN/8),256,0,stream>>>(coords, 0, idx);
  edgeconv_k<6,2><<<BB*NN/4,64,0,stream>>>(x0p, 6, 0, idx, w1t, b15+0, w2t, b15+64, xc, 192, 0);
  knn_kernel<64,192><<<BB*(NN/8),256,0,stream>>>(xc, 0, idx);
  edgeconv_k<64,2><<<BB*NN/4,64,0,stream>>>(xc, 192, 0, idx, w3t, b15+128, w4t, b15+192, xc, 192, 64);
  knn_kernel<64,192><<<BB*(NN/8),256,0,stream>>>(xc, 64, idx);
  edgeconv_k<64,1><<<BB*NN/4,64,0,stream>>>(xc, 192, 64, idx, w5t, b15+256, nullptr, nullptr, xc, 192, 128);

  gemm_k<0><<<dim3(BB*NN/64, 1024/64),256,0,stream>>>(xc, 192, w6t, 1024, 192, b6, nullptr, nullptr, 0, gmaxE);
  bias7_kernel<<<dim3(BB,2),256,0,stream>>>(gmaxE, w7, g7, b7p);
  gemm_k<1><<<dim3(BB*NN/64, 512/64),256,0,stream>>>(xc, 192, w7lt, 512, 192, b7, b7p, y7, 512, nullptr);
  gemm_k<2><<<dim3(BB*NN/64, 256/64),256,0,stream>>>(y7, 512, w8t, 256, 512, b8, nullptr, y8, 256, nullptr);
  conv9_kernel<<<BB*NN/64,64,0,stream>>>(y8, w9, out);
}

// Round 18
// 3480.840 us; speedup vs baseline: 1.0852x; 1.0852x over previous
//
#include <hip/hip_runtime.h>
#include <math.h>

#define BB 8
#define NN 4096
#define KNN 20
#define EPSBN 1e-5f

__device__ __forceinline__ float lrelu(float x){ return x > 0.f ? x : 0.2f*x; }
__device__ __forceinline__ unsigned encf(float f){
  unsigned u = __float_as_uint(f);
  return (u & 0x80000000u) ? ~u : (u | 0x80000000u);
}
__device__ __forceinline__ float decf(unsigned u){
  return (u & 0x80000000u) ? __uint_as_float(u & 0x7fffffffu) : __uint_as_float(~u);
}
__device__ __forceinline__ float rdlane(float v, int l){
  return __uint_as_float(__builtin_amdgcn_readlane(__float_as_uint(v), l));
}

// ---- weight prep: dst[i][O..] = src[o][coff+i] * g[o]/sqrt(1+eps) ----
__global__ void prep_w(float* __restrict__ dst, const float* __restrict__ src,
                       int O, int I, int ld, int coff, const float* __restrict__ g){
  int tot = O*I;
  for(int t = blockIdx.x*blockDim.x + threadIdx.x; t < tot; t += gridDim.x*blockDim.x){
    int o = t % O, i = t / O;
    float s = g ? g[o] * (1.0f/sqrtf(1.0f+EPSBN)) : 1.0f;
    dst[(size_t)i*O + o] = src[(size_t)o*ld + coff + i] * s;
  }
}

__global__ void init_gmax(unsigned* __restrict__ g){
  int t = blockIdx.x*blockDim.x + threadIdx.x;
  if(t < BB*1024) g[t] = 0u;
}

__global__ void build_x0(const float* __restrict__ coords, const float* __restrict__ feats,
                         float* __restrict__ x0p){
  int p = blockIdx.x*blockDim.x + threadIdx.x;
  if(p >= BB*NN) return;
  int b = p / NN, n = p % NN;
  x0p[(size_t)p*6+0] = coords[(size_t)p*3+0];
  x0p[(size_t)p*6+1] = coords[(size_t)p*3+1];
  x0p[(size_t)p*6+2] = coords[(size_t)p*3+2];
  #pragma unroll
  for(int cc=0; cc<3; ++cc) x0p[(size_t)p*6+3+cc] = feats[((size_t)b*3+cc)*NN + n];
}

// ---- kNN: 8 queries/block (512 thr, 1 query per wave). Each row load serves
//      8 queries. Selection = per-lane 3-deep sorted register stack built
//      during the fill; 20 rounds of exact butterfly + owner pop; rare
//      bitwise-identical refill. Lane owns j with (j&255)>>2 == l.
//      [R14 champion configuration — measured optimum, do not modify] ----
template<int D, int LD>
__global__ __launch_bounds__(512,4) void knn_kernel(const float* __restrict__ X, int coloff,
                                                    int* __restrict__ idxOut){
  constexpr int IG = 8;
  __shared__ float stage[2][IG][512];
  __shared__ float xi_s[IG][(D+3)&~3];
  __shared__ float sqi_s[IG];
  const int t = threadIdx.x;
  const int w = t >> 6, l = t & 63;
  const int b = blockIdx.x / (NN/IG);
  const int i0 = (blockIdx.x % (NN/IG)) * IG;
  const float* Xb = X + (size_t)b*NN*LD + coloff;

  for(int u = t; u < IG*D; u += 512) xi_s[u/D][u%D] = Xb[(size_t)(i0 + u/D)*LD + (u%D)];
  __syncthreads();
  if(t < IG){
    float s = 0.f;
    for(int d=0; d<D; ++d){ float v = xi_s[t][d]; s = fmaf(v, v, s); }
    sqi_s[t] = s;
  }
  __syncthreads();

  // per-lane exact top-3 stack (v1 >= v2 >= v3), ties keep smaller index
  float v1=-INFINITY, v2=-INFINITY, v3=-INFINITY;
  int   j1=0x7fffffff, j2=0x7fffffff, j3=0x7fffffff;
  auto ins = [&](float v, int jj){
    bool b1 = v > v1, b2 = v > v2, b3 = v > v3;
    v3 = b3 ? (b2 ? v2 : v) : v3;
    j3 = b3 ? (b2 ? j2 : jj) : j3;
    v2 = b2 ? (b1 ? v1 : v) : v2;
    j2 = b2 ? (b1 ? j1 : jj) : j2;
    v1 = b1 ? v : v1;
    j1 = b1 ? jj : j1;
  };

  for(int s = 0; s < NN/512; ++s){
    const int j = s*512 + t;
    const float* row = Xb + (size_t)j*LD;
    float dot[IG];
    #pragma unroll
    for(int q=0;q<IG;++q) dot[q] = 0.f;
    float sqj = 0.f;
    if constexpr (D % 4 == 0){
      #pragma unroll
      for(int d0=0; d0<D; d0+=4){
        const float4 v = *reinterpret_cast<const float4*>(row + d0);
        sqj = fmaf(v.x,v.x,sqj); sqj = fmaf(v.y,v.y,sqj);
        sqj = fmaf(v.z,v.z,sqj); sqj = fmaf(v.w,v.w,sqj);
        #pragma unroll
        for(int q=0;q<IG;++q){
          const float4 xw = *reinterpret_cast<const float4*>(&xi_s[q][d0]);
          float a = dot[q];
          a = fmaf(v.x,xw.x,a); a = fmaf(v.y,xw.y,a);
          a = fmaf(v.z,xw.z,a); a = fmaf(v.w,xw.w,a);
          dot[q] = a;
        }
      }
    } else {
      #pragma unroll
      for(int d0=0; d0<D; ++d0){
        float v = row[d0];
        sqj = fmaf(v,v,sqj);
        #pragma unroll
        for(int q=0;q<IG;++q) dot[q] = fmaf(v, xi_s[q][d0], dot[q]);
      }
    }
    const int buf = s & 1;
    #pragma unroll
    for(int q=0;q<IG;++q)
      stage[buf][q][t] = 2.f*dot[q] - sqj - sqi_s[q];
    __syncthreads();
    {
      const float4 va = *reinterpret_cast<const float4*>(&stage[buf][w][4*l]);
      const int ja = s*512 + 4*l;
      ins(va.x, ja+0); ins(va.y, ja+1); ins(va.z, ja+2); ins(va.w, ja+3);
      const float4 vb = *reinterpret_cast<const float4*>(&stage[buf][w][256 + 4*l]);
      const int jb2 = s*512 + 256 + 4*l;
      ins(vb.x, jb2+0); ins(vb.y, jb2+1); ins(vb.z, jb2+2); ins(vb.w, jb2+3);
    }
  }

  int* outRow = idxOut + (size_t)(b*NN + i0 + w)*KNN;
  const float sqi = sqi_s[w];
  #pragma unroll 1
  for(int r=0;r<KNN;++r){
    float bv = v1; int bj = j1;
    #pragma unroll
    for(int off = 1; off < 64; off <<= 1){
      float ov = __shfl_xor(bv, off, 64);
      int oj = __shfl_xor(bj, off, 64);
      bool better = (ov > bv) || (ov == bv && oj < bj);
      bv = better ? ov : bv;
      bj = better ? oj : bj;
    }
    if(l == 0) outRow[r] = bj;
    if(((bj & 255) >> 2) == l){
      const float ve = v1; const int je = j1;
      v1=v2; j1=j2; v2=v3; j2=j3; v3=-INFINITY; j3=0x7fffffff;
      if(j1 == 0x7fffffff){
        // refill: exact top-3 of my 64 elems with key strictly worse than (ve,je)
        #pragma unroll 1
        for(int s2=0; s2<NN/512; ++s2){
          #pragma unroll 1
          for(int h=0; h<2; ++h){
            #pragma unroll
            for(int e=0; e<4; ++e){
              const int jj = s2*512 + h*256 + 4*l + e;
              const float* rowp = Xb + (size_t)jj*LD;
              float dotv=0.f, sq=0.f;
              if constexpr (D % 4 == 0){
                #pragma unroll 4
                for(int d0=0; d0<D; d0+=4){
                  const float4 v = *reinterpret_cast<const float4*>(rowp + d0);
                  sq = fmaf(v.x,v.x,sq); sq = fmaf(v.y,v.y,sq);
                  sq = fmaf(v.z,v.z,sq); sq = fmaf(v.w,v.w,sq);
                  const float4 xw = *reinterpret_cast<const float4*>(&xi_s[w][d0]);
                  dotv = fmaf(v.x,xw.x,dotv); dotv = fmaf(v.y,xw.y,dotv);
                  dotv = fmaf(v.z,xw.z,dotv); dotv = fmaf(v.w,xw.w,dotv);
                }
              } else {
                #pragma unroll
                for(int d0=0; d0<D; ++d0){
                  float v = rowp[d0];
                  sq = fmaf(v,v,sq);
                  dotv = fmaf(v, xi_s[w][d0], dotv);
                }
              }
              const float dq = 2.f*dotv - sq - sqi;
              const bool ok = (dq < ve) || (dq == ve && jj > je);
              if(ok) ins(dq, jj);
            }
          }
        }
      }
    }
  }
}

// ---- EdgeConv: weights in registers, readlane broadcasts, no LDS, no barriers ----
template<int DIN, int NL>
__global__ __launch_bounds__(64,3) void edgeconv_k(
    const float* __restrict__ xin, int ldin, int cin_off,
    const int* __restrict__ idx,
    const float* __restrict__ WaT, const float* __restrict__ ba,
    const float* __restrict__ WbT, const float* __restrict__ bb,
    float* __restrict__ xout, int ldout, int cout_off){
  constexpr int PPB = 4;
  const int c = threadIdx.x;           // output channel 0..63
  float wa[DIN];
  #pragma unroll
  for(int d=0; d<DIN; ++d) wa[d] = WaT[d*64 + c];
  float wb[(NL==2)?64:1];
  if constexpr (NL==2){
    #pragma unroll
    for(int d=0; d<64; ++d) wb[d] = WbT[d*64 + c];
  }
  const float bac = ba[c];
  const float bbc = (NL==2) ? bb[c] : 0.f;

  for(int pp=0; pp<PPB; ++pp){
    const int p = blockIdx.x*PPB + pp;
    const int b = p / NN;
    float ctr = (c < DIN) ? xin[(size_t)p*ldin + cin_off + c] : 0.f;
    float bacc[4] = {};
    #pragma unroll
    for(int d=0; d<DIN; ++d)
      bacc[d&3] += rdlane(ctr, d) * (WaT[(DIN+d)*64 + c] - wa[d]);
    const float base = bacc[0]+bacc[1]+bacc[2]+bacc[3];

    const int* irow = idx + (size_t)p*KNN;
    int myidx = (c < KNN) ? irow[c] : 0;
    float vmax = -INFINITY;
    int j0 = __builtin_amdgcn_readlane(myidx, 0);
    float nbr = (c < DIN) ? xin[(size_t)(b*NN + j0)*ldin + cin_off + c] : 0.f;
    for(int k=0; k<KNN; ++k){
      float nbrn = 0.f;
      if(k+1 < KNN){
        int jn = __builtin_amdgcn_readlane(myidx, k+1);
        nbrn = (c < DIN) ? xin[(size_t)(b*NN + jn)*ldin + cin_off + c] : 0.f;
      }
      float hacc[4] = {};
      #pragma unroll
      for(int d=0; d<DIN; ++d) hacc[d&3] += rdlane(nbr, d) * wa[d];
      float a1 = lrelu(base + hacc[0]+hacc[1]+hacc[2]+hacc[3] + bac);
      if constexpr (NL==2){
        float g[4] = {};
        #pragma unroll
        for(int d=0; d<64; ++d) g[d&3] += rdlane(a1, d) * wb[d];
        vmax = fmaxf(vmax, lrelu(g[0]+g[1]+g[2]+g[3] + bbc));
      } else {
        vmax = fmaxf(vmax, a1);
      }
      nbr = nbrn;
    }
    xout[(size_t)p*ldout + cout_off + c] = vmax;
  }
}

// ---- generic fp32 GEMM: C[M][Nw] = A[M][K] @ Bm[K][Nw], 64x64 tile, 4x4 microtile ----
template<int EPI>
__global__ __launch_bounds__(256) void gemm_k(
    const float* __restrict__ A, int lda,
    const float* __restrict__ Bm, int Nw, int Ksz,
    const float* __restrict__ bias_n, const float* __restrict__ bias_bn,
    float* __restrict__ C, int ldc, unsigned* __restrict__ gmaxE){
  constexpr int ST = 68;
  __shared__ float At[32*ST];
  __shared__ float Bt[32*ST];
  const int t = threadIdx.x;
  const int m0 = blockIdx.x * 64;
  const int n0 = blockIdx.y * 64;
  const int tm = t >> 4, tn = t & 15;
  float acc[4][4] = {};
  for(int k0 = 0; k0 < Ksz; k0 += 32){
    #pragma unroll
    for(int r=0;r<2;++r){
      int lin = r*256 + t;
      int m = lin >> 3, f4 = lin & 7;
      float4 v = *reinterpret_cast<const float4*>(A + (size_t)(m0+m)*lda + k0 + f4*4);
      At[(f4*4+0)*ST + m] = v.x; At[(f4*4+1)*ST + m] = v.y;
      At[(f4*4+2)*ST + m] = v.z; At[(f4*4+3)*ST + m] = v.w;
    }
    #pragma unroll
    for(int r=0;r<2;++r){
      int lin = r*256 + t;
      int kk = lin >> 4, n4 = lin & 15;
      float4 v = *reinterpret_cast<const float4*>(Bm + (size_t)(k0+kk)*Nw + n0 + n4*4);
      *reinterpret_cast<float4*>(&Bt[kk*ST + n4*4]) = v;
    }
    __syncthreads();
    #pragma unroll
    for(int kk=0; kk<32; ++kk){
      float4 a4 = *reinterpret_cast<const float4*>(&At[kk*ST + tm*4]);
      float4 b4 = *reinterpret_cast<const float4*>(&Bt[kk*ST + tn*4]);
      float av[4] = {a4.x,a4.y,a4.z,a4.w};
      float bw[4] = {b4.x,b4.y,b4.z,b4.w};
      #pragma unroll
      for(int i2=0;i2<4;++i2)
        #pragma unroll
        for(int q=0;q<4;++q) acc[i2][q] += av[i2]*bw[q];
    }
    __syncthreads();
  }
  const int b = m0 / NN;
  if constexpr (EPI == 0){
    float* colm = At;  // reuse (post-barrier)
    #pragma unroll
    for(int q=0;q<4;++q){
      int n = n0 + tn*4 + q;
      float bn = bias_n[n];
      float mx = -INFINITY;
      #pragma unroll
      for(int r2=0;r2<4;++r2) mx = fmaxf(mx, lrelu(acc[r2][q] + bn));
      colm[tm*64 + tn*4 + q] = mx;
    }
    __syncthreads();
    if(t < 64){
      float mx = -INFINITY;
      #pragma unroll
      for(int r2=0;r2<16;++r2) mx = fmaxf(mx, colm[r2*64 + t]);
      atomicMax(gmaxE + b*1024 + n0 + t, encf(mx));
    }
  } else {
    #pragma unroll
    for(int r2=0;r2<4;++r2){
      int row = m0 + tm*4 + r2;
      float4 vo;
      float vv[4];
      #pragma unroll
      for(int q=0;q<4;++q){
        int n = n0 + tn*4 + q;
        float v = acc[r2][q];
        if constexpr (EPI == 1) v += bias_bn[b*512 + n] + bias_n[n];
        else v += bias_n[n];
        vv[q] = lrelu(v);
      }
      vo.x=vv[0]; vo.y=vv[1]; vo.z=vv[2]; vo.w=vv[3];
      *reinterpret_cast<float4*>(C + (size_t)row*ldc + n0 + tn*4) = vo;
    }
  }
}

// ---- bias7[b][o] = s7[o] * sum_c w7[o][c] * gmax[b][c] ----
__global__ __launch_bounds__(256) void bias7_kernel(const unsigned* __restrict__ gmaxE,
    const float* __restrict__ w7, const float* __restrict__ g7, float* __restrict__ b7p){
  __shared__ float gm[1024];
  const int t = threadIdx.x;
  const int b = blockIdx.x, half = blockIdx.y;
  for(int u=t; u<1024; u+=256) gm[u] = decf(gmaxE[b*1024+u]);
  __syncthreads();
  const int o = half*256 + t;
  const float* row = w7 + (size_t)o*1216;
  float acc = 0.f;
  for(int d0=0; d0<1024; d0+=4){
    float4 v = *reinterpret_cast<const float4*>(row + d0);
    acc += v.x*gm[d0] + v.y*gm[d0+1] + v.z*gm[d0+2] + v.w*gm[d0+3];
  }
  b7p[b*512+o] = acc * (g7[o] * (1.0f/sqrtf(1.0f+EPSBN)));
}

// ---- conv9: [32768][256] @ w9^T[256][20] -> out[32768][20] ----
__global__ __launch_bounds__(64) void conv9_kernel(const float* __restrict__ y8,
    const float* __restrict__ w9, float* __restrict__ out){
  const int p = blockIdx.x*64 + threadIdx.x;
  float acc[20] = {};
  const float* row = y8 + (size_t)p*256;
  for(int d0=0; d0<256; d0+=4){
    float4 v = *reinterpret_cast<const float4*>(row + d0);
    #pragma unroll
    for(int o=0;o<20;++o){
      float4 w = *reinterpret_cast<const float4*>(w9 + o*256 + d0);
      acc[o] += v.x*w.x + v.y*w.y + v.z*w.z + v.w*w.w;
    }
  }
  #pragma unroll
  for(int o=0;o<20;++o) out[(size_t)p*20+o] = acc[o];
}

extern "C" void kernel_launch(void* const* d_in, const int* in_sizes, int n_in,
                              void* d_out, int out_size, void* d_ws, size_t ws_size,
                              hipStream_t stream){
  const float* coords = (const float*)d_in[0];
  const float* feats  = (const float*)d_in[1];
  const float* w1 = (const float*)d_in[2];
  const float* w2 = (const float*)d_in[3];
  const float* w3 = (const float*)d_in[4];
  const float* w4 = (const float*)d_in[5];
  const float* w5 = (const float*)d_in[6];
  const float* w6 = (const float*)d_in[7];
  const float* w7 = (const float*)d_in[8];
  const float* w8 = (const float*)d_in[9];
  const float* w9 = (const float*)d_in[10];
  const float* g15 = (const float*)d_in[11];
  const float* b15 = (const float*)d_in[12];
  const float* g6 = (const float*)d_in[13];
  const float* b6 = (const float*)d_in[14];
  const float* g7 = (const float*)d_in[15];
  const float* b7 = (const float*)d_in[16];
  const float* g8 = (const float*)d_in[17];
  const float* b8 = (const float*)d_in[18];
  float* out = (float*)d_out;
  float* ws = (float*)d_ws;

  size_t off = 0;
  float* xc   = ws + off; off += (size_t)BB*NN*192;
  float* x0p  = ws + off; off += (size_t)BB*NN*6;
  int*   idx  = (int*)(ws + off); off += (size_t)BB*NN*KNN;
  unsigned* gmaxE = (unsigned*)(ws + off); off += BB*1024;
  float* b7p  = ws + off; off += BB*512;
  float* w1t  = ws + off; off += 12*64;
  float* w2t  = ws + off; off += 64*64;
  float* w3t  = ws + off; off += 128*64;
  float* w4t  = ws + off; off += 64*64;
  float* w5t  = ws + off; off += 128*64;
  float* w6t  = ws + off; off += (size_t)192*1024;
  float* w7lt = ws + off; off += (size_t)192*512;
  float* w8t  = ws + off; off += (size_t)512*256;
  float* y7   = ws + off; off += (size_t)BB*NN*512;
  float* y8   = ws + off; off += (size_t)BB*NN*256;

  auto gb = [](int n){ return dim3((unsigned)((n + 255)/256)); };

  prep_w<<<gb(64*12),  256,0,stream>>>(w1t, w1, 64, 12, 12, 0, g15 + 0);
  prep_w<<<gb(64*64),  256,0,stream>>>(w2t, w2, 64, 64, 64, 0, g15 + 64);
  prep_w<<<gb(64*128), 256,0,stream>>>(w3t, w3, 64, 128, 128, 0, g15 + 128);
  prep_w<<<gb(64*64),  256,0,stream>>>(w4t, w4, 64, 64, 64, 0, g15 + 192);
  prep_w<<<gb(64*128), 256,0,stream>>>(w5t, w5, 64, 128, 128, 0, g15 + 256);
  prep_w<<<gb(1024*192),256,0,stream>>>(w6t, w6, 1024, 192, 192, 0, g6);
  prep_w<<<gb(512*192),256,0,stream>>>(w7lt, w7, 512, 192, 1216, 1024, g7);
  prep_w<<<gb(256*512),256,0,stream>>>(w8t, w8, 256, 512, 512, 0, g8);
  init_gmax<<<gb(BB*1024),256,0,stream>>>(gmaxE);
  build_x0<<<gb(BB*NN),256,0,stream>>>(coords, feats, x0p);

  knn_kernel<3,3><<<BB*(NN/8),512,0,stream>>>(coords, 0, idx);
  edgeconv_k<6,2><<<BB*NN/4,64,0,stream>>>(x0p, 6, 0, idx, w1t, b15+0, w2t, b15+64, xc, 192, 0);
  knn_kernel<64,192><<<BB*(NN/8),512,0,stream>>>(xc, 0, idx);
  edgeconv_k<64,2><<<BB*NN/4,64,0,stream>>>(xc, 192, 0, idx, w3t, b15+128, w4t, b15+192, xc, 192, 64);
  knn_kernel<64,192><<<BB*(NN/8),512,0,stream>>>(xc, 64, idx);
  edgeconv_k<64,1><<<BB*NN/4,64,0,stream>>>(xc, 192, 64, idx, w5t, b15+256, nullptr, nullptr, xc, 192, 128);

  gemm_k<0><<<dim3(BB*NN/64, 1024/64),256,0,stream>>>(xc, 192, w6t, 1024, 192, b6, nullptr, nullptr, 0, gmaxE);
  bias7_kernel<<<dim3(BB,2),256,0,stream>>>(gmaxE, w7, g7, b7p);
  gemm_k<1><<<dim3(BB*NN/64, 512/64),256,0,stream>>>(xc, 192, w7lt, 512, 192, b7, b7p, y7, 512, nullptr);
  gemm_k<2><<<dim3(BB*NN/64, 256/64),256,0,stream>>>(y7, 512, w8t, 256, 512, b8, nullptr, y8, 256, nullptr);
  conv9_kernel<<<BB*NN/64,64,0,stream>>>(y8, w9, out);
}

// Round 19
// 3476.411 us; speedup vs baseline: 1.0866x; 1.0013x over previous
//
#include <hip/hip_runtime.h>
#include <math.h>

#define BB 8
#define NN 4096
#define KNN 20
#define EPSBN 1e-5f

__device__ __forceinline__ float lrelu(float x){ return x > 0.f ? x : 0.2f*x; }
__device__ __forceinline__ unsigned encf(float f){
  unsigned u = __float_as_uint(f);
  return (u & 0x80000000u) ? ~u : (u | 0x80000000u);
}
__device__ __forceinline__ float decf(unsigned u){
  return (u & 0x80000000u) ? __uint_as_float(u & 0x7fffffffu) : __uint_as_float(~u);
}
__device__ __forceinline__ float rdlane(float v, int l){
  return __uint_as_float(__builtin_amdgcn_readlane(__float_as_uint(v), l));
}

// ---- weight prep: dst[i][O..] = src[o][coff+i] * g[o]/sqrt(1+eps) ----
__global__ void prep_w(float* __restrict__ dst, const float* __restrict__ src,
                       int O, int I, int ld, int coff, const float* __restrict__ g){
  int tot = O*I;
  for(int t = blockIdx.x*blockDim.x + threadIdx.x; t < tot; t += gridDim.x*blockDim.x){
    int o = t % O, i = t / O;
    float s = g ? g[o] * (1.0f/sqrtf(1.0f+EPSBN)) : 1.0f;
    dst[(size_t)i*O + o] = src[(size_t)o*ld + coff + i] * s;
  }
}

__global__ void init_gmax(unsigned* __restrict__ g){
  int t = blockIdx.x*blockDim.x + threadIdx.x;
  if(t < BB*1024) g[t] = 0u;
}

// also writes zero-padded coords4[p*4] so kNN-1 can use the vector (D%4==0) path
__global__ void build_x0(const float* __restrict__ coords, const float* __restrict__ feats,
                         float* __restrict__ x0p, float* __restrict__ coords4){
  int p = blockIdx.x*blockDim.x + threadIdx.x;
  if(p >= BB*NN) return;
  int b = p / NN, n = p % NN;
  float cx = coords[(size_t)p*3+0];
  float cy = coords[(size_t)p*3+1];
  float cz = coords[(size_t)p*3+2];
  x0p[(size_t)p*6+0] = cx;
  x0p[(size_t)p*6+1] = cy;
  x0p[(size_t)p*6+2] = cz;
  #pragma unroll
  for(int cc=0; cc<3; ++cc) x0p[(size_t)p*6+3+cc] = feats[((size_t)b*3+cc)*NN + n];
  float4 c4; c4.x = cx; c4.y = cy; c4.z = cz; c4.w = 0.f;
  *reinterpret_cast<float4*>(coords4 + (size_t)p*4) = c4;
}

// ---- kNN: 8 queries/block (512 thr, 1 query per wave). Each row load serves
//      8 queries. Selection = per-lane 3-deep sorted register stack built
//      during the fill; 20 rounds of exact butterfly + owner pop; rare
//      bitwise-identical refill. Lane owns j with (j&255)>>2 == l.
//      [R14 champion configuration — measured optimum, do not modify] ----
template<int D, int LD>
__global__ __launch_bounds__(512,4) void knn_kernel(const float* __restrict__ X, int coloff,
                                                    int* __restrict__ idxOut){
  constexpr int IG = 8;
  __shared__ float stage[2][IG][512];
  __shared__ float xi_s[IG][(D+3)&~3];
  __shared__ float sqi_s[IG];
  const int t = threadIdx.x;
  const int w = t >> 6, l = t & 63;
  const int b = blockIdx.x / (NN/IG);
  const int i0 = (blockIdx.x % (NN/IG)) * IG;
  const float* Xb = X + (size_t)b*NN*LD + coloff;

  for(int u = t; u < IG*D; u += 512) xi_s[u/D][u%D] = Xb[(size_t)(i0 + u/D)*LD + (u%D)];
  __syncthreads();
  if(t < IG){
    float s = 0.f;
    for(int d=0; d<D; ++d){ float v = xi_s[t][d]; s = fmaf(v, v, s); }
    sqi_s[t] = s;
  }
  __syncthreads();

  // per-lane exact top-3 stack (v1 >= v2 >= v3), ties keep smaller index
  float v1=-INFINITY, v2=-INFINITY, v3=-INFINITY;
  int   j1=0x7fffffff, j2=0x7fffffff, j3=0x7fffffff;
  auto ins = [&](float v, int jj){
    bool b1 = v > v1, b2 = v > v2, b3 = v > v3;
    v3 = b3 ? (b2 ? v2 : v) : v3;
    j3 = b3 ? (b2 ? j2 : jj) : j3;
    v2 = b2 ? (b1 ? v1 : v) : v2;
    j2 = b2 ? (b1 ? j1 : jj) : j2;
    v1 = b1 ? v : v1;
    j1 = b1 ? jj : j1;
  };

  for(int s = 0; s < NN/512; ++s){
    const int j = s*512 + t;
    const float* row = Xb + (size_t)j*LD;
    float dot[IG];
    #pragma unroll
    for(int q=0;q<IG;++q) dot[q] = 0.f;
    float sqj = 0.f;
    if constexpr (D % 4 == 0){
      #pragma unroll
      for(int d0=0; d0<D; d0+=4){
        const float4 v = *reinterpret_cast<const float4*>(row + d0);
        sqj = fmaf(v.x,v.x,sqj); sqj = fmaf(v.y,v.y,sqj);
        sqj = fmaf(v.z,v.z,sqj); sqj = fmaf(v.w,v.w,sqj);
        #pragma unroll
        for(int q=0;q<IG;++q){
          const float4 xw = *reinterpret_cast<const float4*>(&xi_s[q][d0]);
          float a = dot[q];
          a = fmaf(v.x,xw.x,a); a = fmaf(v.y,xw.y,a);
          a = fmaf(v.z,xw.z,a); a = fmaf(v.w,xw.w,a);
          dot[q] = a;
        }
      }
    } else {
      #pragma unroll
      for(int d0=0; d0<D; ++d0){
        float v = row[d0];
        sqj = fmaf(v,v,sqj);
        #pragma unroll
        for(int q=0;q<IG;++q) dot[q] = fmaf(v, xi_s[q][d0], dot[q]);
      }
    }
    const int buf = s & 1;
    #pragma unroll
    for(int q=0;q<IG;++q)
      stage[buf][q][t] = 2.f*dot[q] - sqj - sqi_s[q];
    __syncthreads();
    {
      const float4 va = *reinterpret_cast<const float4*>(&stage[buf][w][4*l]);
      const int ja = s*512 + 4*l;
      ins(va.x, ja+0); ins(va.y, ja+1); ins(va.z, ja+2); ins(va.w, ja+3);
      const float4 vb = *reinterpret_cast<const float4*>(&stage[buf][w][256 + 4*l]);
      const int jb2 = s*512 + 256 + 4*l;
      ins(vb.x, jb2+0); ins(vb.y, jb2+1); ins(vb.z, jb2+2); ins(vb.w, jb2+3);
    }
  }

  int* outRow = idxOut + (size_t)(b*NN + i0 + w)*KNN;
  const float sqi = sqi_s[w];
  #pragma unroll 1
  for(int r=0;r<KNN;++r){
    float bv = v1; int bj = j1;
    #pragma unroll
    for(int off = 1; off < 64; off <<= 1){
      float ov = __shfl_xor(bv, off, 64);
      int oj = __shfl_xor(bj, off, 64);
      bool better = (ov > bv) || (ov == bv && oj < bj);
      bv = better ? ov : bv;
      bj = better ? oj : bj;
    }
    if(l == 0) outRow[r] = bj;
    if(((bj & 255) >> 2) == l){
      const float ve = v1; const int je = j1;
      v1=v2; j1=j2; v2=v3; j2=j3; v3=-INFINITY; j3=0x7fffffff;
      if(j1 == 0x7fffffff){
        // refill: exact top-3 of my 64 elems with key strictly worse than (ve,je)
        #pragma unroll 1
        for(int s2=0; s2<NN/512; ++s2){
          #pragma unroll 1
          for(int h=0; h<2; ++h){
            #pragma unroll
            for(int e=0; e<4; ++e){
              const int jj = s2*512 + h*256 + 4*l + e;
              const float* rowp = Xb + (size_t)jj*LD;
              float dotv=0.f, sq=0.f;
              if constexpr (D % 4 == 0){
                #pragma unroll 4
                for(int d0=0; d0<D; d0+=4){
                  const float4 v = *reinterpret_cast<const float4*>(rowp + d0);
                  sq = fmaf(v.x,v.x,sq); sq = fmaf(v.y,v.y,sq);
                  sq = fmaf(v.z,v.z,sq); sq = fmaf(v.w,v.w,sq);
                  const float4 xw = *reinterpret_cast<const float4*>(&xi_s[w][d0]);
                  dotv = fmaf(v.x,xw.x,dotv); dotv = fmaf(v.y,xw.y,dotv);
                  dotv = fmaf(v.z,xw.z,dotv); dotv = fmaf(v.w,xw.w,dotv);
                }
              } else {
                #pragma unroll
                for(int d0=0; d0<D; ++d0){
                  float v = rowp[d0];
                  sq = fmaf(v,v,sq);
                  dotv = fmaf(v, xi_s[w][d0], dotv);
                }
              }
              const float dq = 2.f*dotv - sq - sqi;
              const bool ok = (dq < ve) || (dq == ve && jj > je);
              if(ok) ins(dq, jj);
            }
          }
        }
      }
    }
  }
}

// ---- EdgeConv: weights in registers, readlane broadcasts, no LDS, no barriers ----
template<int DIN, int NL>
__global__ __launch_bounds__(64,3) void edgeconv_k(
    const float* __restrict__ xin, int ldin, int cin_off,
    const int* __restrict__ idx,
    const float* __restrict__ WaT, const float* __restrict__ ba,
    const float* __restrict__ WbT, const float* __restrict__ bb,
    float* __restrict__ xout, int ldout, int cout_off){
  constexpr int PPB = 4;
  const int c = threadIdx.x;           // output channel 0..63
  float wa[DIN];
  #pragma unroll
  for(int d=0; d<DIN; ++d) wa[d] = WaT[d*64 + c];
  float wb[(NL==2)?64:1];
  if constexpr (NL==2){
    #pragma unroll
    for(int d=0; d<64; ++d) wb[d] = WbT[d*64 + c];
  }
  const float bac = ba[c];
  const float bbc = (NL==2) ? bb[c] : 0.f;

  for(int pp=0; pp<PPB; ++pp){
    const int p = blockIdx.x*PPB + pp;
    const int b = p / NN;
    float ctr = (c < DIN) ? xin[(size_t)p*ldin + cin_off + c] : 0.f;
    float bacc[4] = {};
    #pragma unroll
    for(int d=0; d<DIN; ++d)
      bacc[d&3] += rdlane(ctr, d) * (WaT[(DIN+d)*64 + c] - wa[d]);
    const float base = bacc[0]+bacc[1]+bacc[2]+bacc[3];

    const int* irow = idx + (size_t)p*KNN;
    int myidx = (c < KNN) ? irow[c] : 0;
    float vmax = -INFINITY;
    int j0 = __builtin_amdgcn_readlane(myidx, 0);
    float nbr = (c < DIN) ? xin[(size_t)(b*NN + j0)*ldin + cin_off + c] : 0.f;
    for(int k=0; k<KNN; ++k){
      float nbrn = 0.f;
      if(k+1 < KNN){
        int jn = __builtin_amdgcn_readlane(myidx, k+1);
        nbrn = (c < DIN) ? xin[(size_t)(b*NN + jn)*ldin + cin_off + c] : 0.f;
      }
      float hacc[4] = {};
      #pragma unroll
      for(int d=0; d<DIN; ++d) hacc[d&3] += rdlane(nbr, d) * wa[d];
      float a1 = lrelu(base + hacc[0]+hacc[1]+hacc[2]+hacc[3] + bac);
      if constexpr (NL==2){
        float g[4] = {};
        #pragma unroll
        for(int d=0; d<64; ++d) g[d&3] += rdlane(a1, d) * wb[d];
        vmax = fmaxf(vmax, lrelu(g[0]+g[1]+g[2]+g[3] + bbc));
      } else {
        vmax = fmaxf(vmax, a1);
      }
      nbr = nbrn;
    }
    xout[(size_t)p*ldout + cout_off + c] = vmax;
  }
}

// ---- generic fp32 GEMM: C[M][Nw] = A[M][K] @ Bm[K][Nw], 64x64 tile, 4x4 microtile ----
template<int EPI>
__global__ __launch_bounds__(256) void gemm_k(
    const float* __restrict__ A, int lda,
    const float* __restrict__ Bm, int Nw, int Ksz,
    const float* __restrict__ bias_n, const float* __restrict__ bias_bn,
    float* __restrict__ C, int ldc, unsigned* __restrict__ gmaxE){
  constexpr int ST = 68;
  __shared__ float At[32*ST];
  __shared__ float Bt[32*ST];
  const int t = threadIdx.x;
  const int m0 = blockIdx.x * 64;
  const int n0 = blockIdx.y * 64;
  const int tm = t >> 4, tn = t & 15;
  float acc[4][4] = {};
  for(int k0 = 0; k0 < Ksz; k0 += 32){
    #pragma unroll
    for(int r=0;r<2;++r){
      int lin = r*256 + t;
      int m = lin >> 3, f4 = lin & 7;
      float4 v = *reinterpret_cast<const float4*>(A + (size_t)(m0+m)*lda + k0 + f4*4);
      At[(f4*4+0)*ST + m] = v.x; At[(f4*4+1)*ST + m] = v.y;
      At[(f4*4+2)*ST + m] = v.z; At[(f4*4+3)*ST + m] = v.w;
    }
    #pragma unroll
    for(int r=0;r<2;++r){
      int lin = r*256 + t;
      int kk = lin >> 4, n4 = lin & 15;
      float4 v = *reinterpret_cast<const float4*>(Bm + (size_t)(k0+kk)*Nw + n0 + n4*4);
      *reinterpret_cast<float4*>(&Bt[kk*ST + n4*4]) = v;
    }
    __syncthreads();
    #pragma unroll
    for(int kk=0; kk<32; ++kk){
      float4 a4 = *reinterpret_cast<const float4*>(&At[kk*ST + tm*4]);
      float4 b4 = *reinterpret_cast<const float4*>(&Bt[kk*ST + tn*4]);
      float av[4] = {a4.x,a4.y,a4.z,a4.w};
      float bw[4] = {b4.x,b4.y,b4.z,b4.w};
      #pragma unroll
      for(int i2=0;i2<4;++i2)
        #pragma unroll
        for(int q=0;q<4;++q) acc[i2][q] += av[i2]*bw[q];
    }
    __syncthreads();
  }
  const int b = m0 / NN;
  if constexpr (EPI == 0){
    float* colm = At;  // reuse (post-barrier)
    #pragma unroll
    for(int q=0;q<4;++q){
      int n = n0 + tn*4 + q;
      float bn = bias_n[n];
      float mx = -INFINITY;
      #pragma unroll
      for(int r2=0;r2<4;++r2) mx = fmaxf(mx, lrelu(acc[r2][q] + bn));
      colm[tm*64 + tn*4 + q] = mx;
    }
    __syncthreads();
    if(t < 64){
      float mx = -INFINITY;
      #pragma unroll
      for(int r2=0;r2<16;++r2) mx = fmaxf(mx, colm[r2*64 + t]);
      atomicMax(gmaxE + b*1024 + n0 + t, encf(mx));
    }
  } else {
    #pragma unroll
    for(int r2=0;r2<4;++r2){
      int row = m0 + tm*4 + r2;
      float4 vo;
      float vv[4];
      #pragma unroll
      for(int q=0;q<4;++q){
        int n = n0 + tn*4 + q;
        float v = acc[r2][q];
        if constexpr (EPI == 1) v += bias_bn[b*512 + n] + bias_n[n];
        else v += bias_n[n];
        vv[q] = lrelu(v);
      }
      vo.x=vv[0]; vo.y=vv[1]; vo.z=vv[2]; vo.w=vv[3];
      *reinterpret_cast<float4*>(C + (size_t)row*ldc + n0 + tn*4) = vo;
    }
  }
}

// ---- bias7[b][o] = s7[o] * sum_c w7[o][c] * gmax[b][c] ----
__global__ __launch_bounds__(256) void bias7_kernel(const unsigned* __restrict__ gmaxE,
    const float* __restrict__ w7, const float* __restrict__ g7, float* __restrict__ b7p){
  __shared__ float gm[1024];
  const int t = threadIdx.x;
  const int b = blockIdx.x, half = blockIdx.y;
  for(int u=t; u<1024; u+=256) gm[u] = decf(gmaxE[b*1024+u]);
  __syncthreads();
  const int o = half*256 + t;
  const float* row = w7 + (size_t)o*1216;
  float acc = 0.f;
  for(int d0=0; d0<1024; d0+=4){
    float4 v = *reinterpret_cast<const float4*>(row + d0);
    acc += v.x*gm[d0] + v.y*gm[d0+1] + v.z*gm[d0+2] + v.w*gm[d0+3];
  }
  b7p[b*512+o] = acc * (g7[o] * (1.0f/sqrtf(1.0f+EPSBN)));
}

// ---- conv9: [32768][256] @ w9^T[256][20] -> out[32768][20] ----
__global__ __launch_bounds__(64) void conv9_kernel(const float* __restrict__ y8,
    const float* __restrict__ w9, float* __restrict__ out){
  const int p = blockIdx.x*64 + threadIdx.x;
  float acc[20] = {};
  const float* row = y8 + (size_t)p*256;
  for(int d0=0; d0<256; d0+=4){
    float4 v = *reinterpret_cast<const float4*>(row + d0);
    #pragma unroll
    for(int o=0;o<20;++o){
      float4 w = *reinterpret_cast<const float4*>(w9 + o*256 + d0);
      acc[o] += v.x*w.x + v.y*w.y + v.z*w.z + v.w*w.w;
    }
  }
  #pragma unroll
  for(int o=0;o<20;++o) out[(size_t)p*20+o] = acc[o];
}

extern "C" void kernel_launch(void* const* d_in, const int* in_sizes, int n_in,
                              void* d_out, int out_size, void* d_ws, size_t ws_size,
                              hipStream_t stream){
  const float* coords = (const float*)d_in[0];
  const float* feats  = (const float*)d_in[1];
  const float* w1 = (const float*)d_in[2];
  const float* w2 = (const float*)d_in[3];
  const float* w3 = (const float*)d_in[4];
  const float* w4 = (const float*)d_in[5];
  const float* w5 = (const float*)d_in[6];
  const float* w6 = (const float*)d_in[7];
  const float* w7 = (const float*)d_in[8];
  const float* w8 = (const float*)d_in[9];
  const float* w9 = (const float*)d_in[10];
  const float* g15 = (const float*)d_in[11];
  const float* b15 = (const float*)d_in[12];
  const float* g6 = (const float*)d_in[13];
  const float* b6 = (const float*)d_in[14];
  const float* g7 = (const float*)d_in[15];
  const float* b7 = (const float*)d_in[16];
  const float* g8 = (const float*)d_in[17];
  const float* b8 = (const float*)d_in[18];
  float* out = (float*)d_out;
  float* ws = (float*)d_ws;

  size_t off = 0;
  float* xc   = ws + off; off += (size_t)BB*NN*192;
  float* x0p  = ws + off; off += (size_t)BB*NN*6;
  int*   idx  = (int*)(ws + off); off += (size_t)BB*NN*KNN;
  unsigned* gmaxE = (unsigned*)(ws + off); off += BB*1024;
  float* b7p  = ws + off; off += BB*512;
  float* coords4 = ws + off; off += (size_t)BB*NN*4;
  float* w1t  = ws + off; off += 12*64;
  float* w2t  = ws + off; off += 64*64;
  float* w3t  = ws + off; off += 128*64;
  float* w4t  = ws + off; off += 64*64;
  float* w5t  = ws + off; off += 128*64;
  float* w6t  = ws + off; off += (size_t)192*1024;
  float* w7lt = ws + off; off += (size_t)192*512;
  float* w8t  = ws + off; off += (size_t)512*256;
  float* y7   = ws + off; off += (size_t)BB*NN*512;
  float* y8   = ws + off; off += (size_t)BB*NN*256;

  auto gb = [](int n){ return dim3((unsigned)((n + 255)/256)); };

  prep_w<<<gb(64*12),  256,0,stream>>>(w1t, w1, 64, 12, 12, 0, g15 + 0);
  prep_w<<<gb(64*64),  256,0,stream>>>(w2t, w2, 64, 64, 64, 0, g15 + 64);
  prep_w<<<gb(64*128), 256,0,stream>>>(w3t, w3, 64, 128, 128, 0, g15 + 128);
  prep_w<<<gb(64*64),  256,0,stream>>>(w4t, w4, 64, 64, 64, 0, g15 + 192);
  prep_w<<<gb(64*128), 256,0,stream>>>(w5t, w5, 64, 128, 128, 0, g15 + 256);
  prep_w<<<gb(1024*192),256,0,stream>>>(w6t, w6, 1024, 192, 192, 0, g6);
  prep_w<<<gb(512*192),256,0,stream>>>(w7lt, w7, 512, 192, 1216, 1024, g7);
  prep_w<<<gb(256*512),256,0,stream>>>(w8t, w8, 256, 512, 512, 0, g8);
  init_gmax<<<gb(BB*1024),256,0,stream>>>(gmaxE);
  build_x0<<<gb(BB*NN),256,0,stream>>>(coords, feats, x0p, coords4);

  knn_kernel<4,4><<<BB*(NN/8),512,0,stream>>>(coords4, 0, idx);
  edgeconv_k<6,2><<<BB*NN/4,64,0,stream>>>(x0p, 6, 0, idx, w1t, b15+0, w2t, b15+64, xc, 192, 0);
  knn_kernel<64,192><<<BB*(NN/8),512,0,stream>>>(xc, 0, idx);
  edgeconv_k<64,2><<<BB*NN/4,64,0,stream>>>(xc, 192, 0, idx, w3t, b15+128, w4t, b15+192, xc, 192, 64);
  knn_kernel<64,192><<<BB*(NN/8),512,0,stream>>>(xc, 64, idx);
  edgeconv_k<64,1><<<BB*NN/4,64,0,stream>>>(xc, 192, 64, idx, w5t, b15+256, nullptr, nullptr, xc, 192, 128);

  gemm_k<0><<<dim3(BB*NN/64, 1024/64),256,0,stream>>>(xc, 192, w6t, 1024, 192, b6, nullptr, nullptr, 0, gmaxE);
  bias7_kernel<<<dim3(BB,2),256,0,stream>>>(gmaxE, w7, g7, b7p);
  gemm_k<1><<<dim3(BB*NN/64, 512/64),256,0,stream>>>(xc, 192, w7lt, 512, 192, b7, b7p, y7, 512, nullptr);
  gemm_k<2><<<dim3(BB*NN/64, 256/64),256,0,stream>>>(y7, 512, w8t, 256, 512, b8, nullptr, y8, 256, nullptr);
  conv9_kernel<<<BB*NN/64,64,0,stream>>>(y8, w9, out);
}